// Round 5
// baseline (679.772 us; speedup 1.0000x reference)
//
#include <hip/hip_runtime.h>
#include <math.h>

// FineGrainLoss: B=96, n1=196 (image tokens), n2=77 (text tokens), d=512.
#define BB 96
#define N1 196
#define N2 77
#define DD 512

#define IMGN (BB * N1 * DD)
#define TXTN (BB * N2 * DD)

// Block = (bi, btPair): 208 x 160 tile (13 A strips, 2x5 B ct tiles).
// R14 REG-STAGING (T14): R4's fat-wave geometry (4 waves, 2x2 grid,
// strip-groups {7,6} x bt-half, acc 35 f4v) but staging is
// global_load_dwordx4 -> VGPR (issued 1.5 steps early) -> ds_write_b128
// placed BETWEEN two compute half-phases. This removes the
// global_load_lds DMA engine entirely — the suspect serial resource:
// R1/R3/R4 all pinned at ~233 µs (slot 3.9k cyc vs compute 1.4k) with
// every pipe <=30%, and the only lever that ever helped was a second
// co-resident block covering the staging stall. 23 real tiles (no dummy:
// reg path has no wave-uniform vmcnt constraint), 2 buffers, ONE
// __syncthreads per step, s_setprio(1) around MFMA clusters (T5: the
// front/stage/tail phase split gives the CU scheduler roles to arbitrate).
#define ATILES 13
#define NTILES 23
#define BUFH (NTILES * 512)  // _Float16 per buffer (23,552 B)

typedef _Float16 f16x8 __attribute__((ext_vector_type(8)));  // 8 f16 (4 VGPR)
typedef float f4v __attribute__((ext_vector_type(4)));       // MFMA C/D

// fp32 -> fp16 convert pass (4 elems/thread), img and txt fused in one launch.
__global__ void convert_kernel(const float* __restrict__ img,
                               const float* __restrict__ txt,
                               _Float16* __restrict__ dst) {
    int i = (blockIdx.x * blockDim.x + threadIdx.x) * 4;
    if (i >= IMGN + TXTN) return;
    const float* src = (i < IMGN) ? (img + i) : (txt + (i - IMGN));
    float4 v = *(const float4*)src;
    union { _Float16 h[4]; uint2 u; } o;
    o.h[0] = (_Float16)v.x; o.h[1] = (_Float16)v.y;
    o.h[2] = (_Float16)v.z; o.h[3] = (_Float16)v.w;
    *(uint2*)(dst + i) = o.u;
}

// One K=32 sub-step: strips [SG0, SG0+NS) x 5 cts of bt-half H.
// A strip s at tile s; B ct of half H at tile ATILES + H*5 + ct.
// acc is pre-offset by the caller so slot = (strip - groupBase)*5 + ct.
template <int SG0, int NS, int H>
__device__ __forceinline__ void compute_sub(const f16x8* __restrict__ fr,
                                            f4v* __restrict__ acc, int lane) {
    f16x8 b[5];
#pragma unroll
    for (int ct = 0; ct < 5; ++ct)
        b[ct] = fr[(ATILES + H * 5 + ct) * 64 + lane];
#pragma unroll
    for (int i = 0; i < NS; ++i) {
        f16x8 a = fr[(SG0 + i) * 64 + lane];
#pragma unroll
        for (int ct = 0; ct < 5; ++ct)
            acc[i * 5 + ct] = __builtin_amdgcn_mfma_f32_16x16x32_f16(
                a, b[ct], acc[i * 5 + ct], 0, 0, 0);
    }
}

// Reduction partials. C/D layout: col = lane&15, row = (lane>>4)*4 + reg.
// rp[H*208 + q]: per-bt-half rowmax (each (H, strip) owned by one wave).
// cp[g*160 + H*80 + col]: colmax partial per strip-group (g = 0..1).
template <int SG0, int NS, int H>
__device__ __forceinline__ void reduce_phase1(const f4v* __restrict__ acc,
                                              int g, int lq, int lm,
                                              float* __restrict__ rp,
                                              float* __restrict__ cp) {
    float colm[5];
#pragma unroll
    for (int ct = 0; ct < 5; ++ct) colm[ct] = -INFINITY;
#pragma unroll
    for (int i = 0; i < NS; ++i) {
        const int s = SG0 + i;
        float rowm[4] = {-INFINITY, -INFINITY, -INFINITY, -INFINITY};
        bool rows_ok = (s != 12) || (lq == 0);   // rows >=196 are clamp-dups
#pragma unroll
        for (int ct = 0; ct < 5; ++ct) {
            f4v a = acc[i * 5 + ct];
            bool col_ok = (ct != 4) || (lm < N2 - 64);   // cols >=77 dups
            float cm = fmaxf(fmaxf(a[0], a[1]), fmaxf(a[2], a[3]));
            colm[ct] = fmaxf(colm[ct], rows_ok ? cm : -INFINITY);
#pragma unroll
            for (int r = 0; r < 4; ++r)
                rowm[r] = fmaxf(rowm[r], col_ok ? a[r] : -INFINITY);
        }
#pragma unroll
        for (int r = 0; r < 4; ++r) {
            float m = rowm[r];
            m = fmaxf(m, __shfl_xor(m, 1));
            m = fmaxf(m, __shfl_xor(m, 2));
            m = fmaxf(m, __shfl_xor(m, 4));
            m = fmaxf(m, __shfl_xor(m, 8));
            if (lm == 0) rp[H * 208 + s * 16 + lq * 4 + r] = m;
        }
    }
#pragma unroll
    for (int ct = 0; ct < 5; ++ct) {
        float m = colm[ct];
        m = fmaxf(m, __shfl_xor(m, 16));
        m = fmaxf(m, __shfl_xor(m, 32));
        if (lq == 0) cp[g * 160 + H * 80 + ct * 16 + lm] = m;
    }
}

// One block per (bi, btPair): S[208x160] = img[bi].(txt[bt0]|txt[bt1])^T.
// 256 threads = 4 waves in a 2x2 grid: strip-groups {7,6} x bt-half.
// __launch_bounds__(256,2): total-reg cap 256/wave; demand ~225 (acc 140
// + 24 staging + frags/addr). Do NOT raise the min-waves arg (R11 lesson:
// forcing occupancy spills acc -> WRITE_SIZE balloons 25,000x).
template <bool PRE>
__global__ __launch_bounds__(256, 2) void sim_mfma_kernel(
    const float* __restrict__ imgF, const float* __restrict__ txtF,
    const _Float16* __restrict__ h16,   // [img | txt] concatenated
    float* __restrict__ i2t, float* __restrict__ t2i)
{
    // ---- XCD-locality swizzle (4608 blocks = 8 xcd x 12 bi x 48 btPairs) ----
    const int id  = blockIdx.x;
    const int xcd = id & 7;
    const int lid = id >> 3;           // 0..575
    const int w   = lid % 48;
    const int btq = lid / 48;          // 0..11
    const int btp = btq * 4 + (w & 3); // 0..47
    const int bi  = xcd * 12 + (w >> 2);
    const int bt0 = btp * 2;

    const int tid = threadIdx.x;
    const int wave = tid >> 6, lane = tid & 63;
    const int lm = lane & 15;
    const int lq = lane >> 4;
    const int g = wave >> 1;           // strip-group 0..1
    // const int h = wave & 1;         // bt-half (baked into templates)

    __shared__ __align__(16) _Float16 lds[2 * BUFH];   // 47,104 B
    // epilogue scratch aliases buffer 0: last compute (kc=15) reads buf 1;
    // buf0's last write was at kc=13 (data for step 14), its last readers
    // (compute(14)) finished before the end-of-step-14 __syncthreads, and
    // all waves pass the end-of-step-15 __syncthreads before reducing.
    float* scratch = (float*)lds;
    float* rp   = scratch;             // 416: [half][208] rowmax
    float* cp   = scratch + 416;       // 320: [g][160] colmax partials
    float* sws  = scratch + 736;       // 4
    float* scol = scratch + 740;       // 160

    // ---- staging descriptors (k-invariant element offsets) ----
    // Thread stages cell `lane` of tile T = 4j + wave, j=0..5 (23 real
    // tiles: waves 0-2 stage 6, wave 3 stages 5). T<13 -> A strip T;
    // 13<=T<23 -> B: ct=T-13, bt = bt0 + (ct>=5).
    int off[6];
    const float* fsrc[6];
#pragma unroll
    for (int j = 0; j < 6; ++j) {
        const int T = 4 * j + wave;
        int o;
        bool isA = true;
        if (T < ATILES) {
            int q = T * 16 + lm; q = q > (N1 - 1) ? (N1 - 1) : q;
            o = (bi * N1 + q) * DD + lq * 8;
        } else if (T < 23) {
            isA = false;
            int ct = T - ATILES;
            int bt = bt0 + (ct >= 5);
            int r = (ct % 5) * 16 + lm; r = r > (N2 - 1) ? (N2 - 1) : r;
            o = (bt * N2 + r) * DD + lq * 8;
        } else {
            o = lq * 8;   // wave 3 j=5: unused (guarded everywhere)
        }
        if constexpr (PRE) {
            off[j] = isA ? o : (IMGN + o);
        } else {
            off[j] = o;
            fsrc[j] = isA ? imgF : txtF;
        }
    }

    f4v acc[35];   // waves 0,1 (7-strip group): 35; waves 2,3: 30 (tail dead)
#pragma unroll
    for (int i = 0; i < 35; ++i) acc[i] = (f4v){0.f, 0.f, 0.f, 0.f};

    // front half: strips {0..3} / {7..9}; tail half: strips {4..6} / {10..12}.
    // acc slot = (strip - groupBase)*5 + ct, so tail gets acc+20 / acc+15.
    auto compute_front = [&](const f16x8* fr) {
        if (wave == 0)      compute_sub<0, 4, 0>(fr, acc, lane);
        else if (wave == 1) compute_sub<0, 4, 1>(fr, acc, lane);
        else if (wave == 2) compute_sub<7, 3, 0>(fr, acc, lane);
        else                compute_sub<7, 3, 1>(fr, acc, lane);
    };
    auto compute_tail = [&](const f16x8* fr) {
        if (wave == 0)      compute_sub<4, 3, 0>(fr, acc + 20, lane);
        else if (wave == 1) compute_sub<4, 3, 1>(fr, acc + 20, lane);
        else if (wave == 2) compute_sub<10, 3, 0>(fr, acc + 15, lane);
        else                compute_sub<10, 3, 1>(fr, acc + 15, lane);
    };

    if constexpr (PRE) {
        // per-tile global base pointers (16B-aligned: off = k*512 + lq*8 f16)
        const uint4* gq[6];
#pragma unroll
        for (int j = 0; j < 6; ++j) gq[j] = (const uint4*)(h16 + off[j]);

        uint4 st[6];   // in-flight K32 slab (24 VGPRs)
        auto reg_load = [&](int kc) {
            const int k4 = kc * 4;   // 32 f16 = 64 B = 4 uint4 per step
#pragma unroll
            for (int j = 0; j < 6; ++j)
                if (4 * j + wave < 23) st[j] = gq[j][k4];
        };
        auto lds_write = [&](int b) {
#pragma unroll
            for (int j = 0; j < 6; ++j)
                if (4 * j + wave < 23)
                    ((uint4*)lds)[(b * NTILES + 4 * j + wave) * 64 + lane]
                        = st[j];
        };

        // ---- K loop: 16 steps of BK=32, 2 buffers, 1 barrier per step.
        // Staging is per-wave private: loads issued 1.5 steps ahead of
        // use; ds_write sits between the two compute half-phases so HBM/L2
        // latency hides under MFMA. WAR on buf cur^1 is ordered by the
        // end-of-previous-step __syncthreads; RAW by the end-of-this-step
        // one (lgkmcnt drained by __syncthreads).
        reg_load(0);
        lds_write(0);
        reg_load(1);
        __syncthreads();
#pragma unroll 1
        for (int kc = 0; kc < 16; ++kc) {
            const f16x8* fr = (const f16x8*)(lds + (kc & 1) * BUFH);
            __builtin_amdgcn_s_setprio(1);
            compute_front(fr);
            __builtin_amdgcn_s_setprio(0);
            asm volatile("" ::: "memory");
            if (kc + 1 < 16) lds_write((kc + 1) & 1);   // st holds kc+1 data
            asm volatile("" ::: "memory");
            if (kc + 2 < 16) reg_load(kc + 2);
            asm volatile("" ::: "memory");
            __builtin_amdgcn_s_setprio(1);
            compute_tail(fr);
            __builtin_amdgcn_s_setprio(0);
            __syncthreads();
        }
    } else {
        // correctness fallback (workspace too small): sync single-buffer
#pragma unroll 1
        for (int kc = 0; kc < 16; ++kc) {
            __syncthreads();
            const int k0 = kc * 32;
#pragma unroll
            for (int j = 0; j < 6; ++j) {
                const int T = 4 * j + wave;
                if (T < 23) {
                    float4 v0 = *(const float4*)(fsrc[j] + off[j] + k0);
                    float4 v1 = *(const float4*)(fsrc[j] + off[j] + k0 + 4);
                    union { f16x8 f; uint4 u; } o;
                    o.f[0] = (_Float16)v0.x; o.f[1] = (_Float16)v0.y;
                    o.f[2] = (_Float16)v0.z; o.f[3] = (_Float16)v0.w;
                    o.f[4] = (_Float16)v1.x; o.f[5] = (_Float16)v1.y;
                    o.f[6] = (_Float16)v1.z; o.f[7] = (_Float16)v1.w;
                    ((uint4*)lds)[T * 64 + lane] = o.u;
                }
            }
            __syncthreads();
            compute_front((const f16x8*)lds);
            compute_tail((const f16x8*)lds);
        }
        __syncthreads();
    }

    // ---- fused reductions (buffer-0 scratch; no race, see decl comment) ----
    if (wave == 0)      reduce_phase1<0, 7, 0>(acc, g, lq, lm, rp, cp);
    else if (wave == 1) reduce_phase1<0, 7, 1>(acc, g, lq, lm, rp, cp);
    else if (wave == 2) reduce_phase1<7, 6, 0>(acc, g, lq, lm, rp, cp);
    else                reduce_phase1<7, 6, 1>(acc, g, lq, lm, rp, cp);
    __syncthreads();

    // i2t: mean over q<196 of rowmax, per bt-half.
    // wave w: half h = w&1, row-segment sseg = w>>1 (rows sseg*128 + lane
    // and +64). qa is always <196; qb needs the guard.
    {
        const int h = wave & 1;
        const int sseg = wave >> 1;
        const int qa = sseg * 128 + lane;
        const int qb = qa + 64;
        float v = rp[h * 208 + qa];
        if (qb < N1) v += rp[h * 208 + qb];
        v += __shfl_xor(v, 1);  v += __shfl_xor(v, 2);  v += __shfl_xor(v, 4);
        v += __shfl_xor(v, 8);  v += __shfl_xor(v, 16); v += __shfl_xor(v, 32);
        if (lane == 0) sws[wave] = v;
    }
    // colmax merge across the 2 strip-groups
    if (tid < 160) scol[tid] = fmaxf(cp[tid], cp[160 + tid]);
    __syncthreads();
    if (tid == 0)
        i2t[bi * BB + bt0] = (sws[0] + sws[2]) * (1.f / (float)N1);
    if (tid == 1)
        i2t[bi * BB + bt0 + 1] = (sws[1] + sws[3]) * (1.f / (float)N1);
    // t2i: mean over r<77 of colmax; wave0 -> bt0 (cols 0-79), wave1 -> bt1.
    if (wave < 2) {
        const float* c = scol + wave * 80;
        float cv = c[lane] + ((lane < N2 - 64) ? c[64 + lane] : 0.f);
        cv += __shfl_xor(cv, 1);  cv += __shfl_xor(cv, 2);  cv += __shfl_xor(cv, 4);
        cv += __shfl_xor(cv, 8);  cv += __shfl_xor(cv, 16); cv += __shfl_xor(cv, 32);
        if (lane == 0)
            t2i[(bt0 + wave) * BB + bi] = cv * (1.f / (float)N2);
    }
}

// CE with arange labels over both [B,B] logit matrices.
__global__ __launch_bounds__(256) void ce_kernel(
    const float* __restrict__ i2t, const float* __restrict__ t2i,
    float* __restrict__ out)
{
    const int tid = threadIdx.x;
    const int wid = tid >> 6;
    const int lane = tid & 63;

    float contrib = 0.f;
    if (tid < 2 * BB) {
        const float* M = (tid < BB) ? i2t : t2i;
        const int b = (tid < BB) ? tid : tid - BB;
        const float* row = M + b * BB;
        float mx = row[0];
#pragma unroll 1
        for (int c = 1; c < BB; ++c) mx = fmaxf(mx, row[c]);
        float s = 0.f;
#pragma unroll 1
        for (int c = 0; c < BB; ++c) s += expf(row[c] - mx);
        float lse = mx + logf(s);
        contrib = row[b] - lse;
    }
    contrib += __shfl_xor(contrib, 1);
    contrib += __shfl_xor(contrib, 2);
    contrib += __shfl_xor(contrib, 4);
    contrib += __shfl_xor(contrib, 8);
    contrib += __shfl_xor(contrib, 16);
    contrib += __shfl_xor(contrib, 32);

    __shared__ float s_part[4];
    if (lane == 0) s_part[wid] = contrib;
    __syncthreads();
    if (tid == 0) {
        float total = s_part[0] + s_part[1] + s_part[2] + s_part[3];
        out[0] = -total * (1.f / (float)(2 * BB));
    }
}

extern "C" void kernel_launch(void* const* d_in, const int* in_sizes, int n_in,
                              void* d_out, int out_size, void* d_ws, size_t ws_size,
                              hipStream_t stream) {
    const float* img = (const float*)d_in[0];   // [96,196,512] fp32
    const float* txt = (const float*)d_in[1];   // [96,77,512] fp32
    float* i2t = (float*)d_ws;                  // [96,96]
    float* t2i = i2t + BB * BB;                 // [96,96]

    const size_t conv_off = 2 * BB * BB * sizeof(float);   // 16B-aligned
    const size_t need = conv_off + (size_t)(IMGN + TXTN) * sizeof(_Float16);

    const int nblocks = BB * (BB / 2);   // 4608 = (bi, btPair)
    if (ws_size >= need) {
        _Float16* h16 = (_Float16*)((char*)d_ws + conv_off);
        const int ntot = (IMGN + TXTN) / 4;
        convert_kernel<<<(ntot + 255) / 256, 256, 0, stream>>>(img, txt, h16);
        sim_mfma_kernel<true><<<nblocks, 256, 0, stream>>>(img, txt, h16, i2t, t2i);
    } else {
        sim_mfma_kernel<false><<<nblocks, 256, 0, stream>>>(img, txt, nullptr, i2t, t2i);
    }
    ce_kernel<<<1, 256, 0, stream>>>(i2t, t2i, (float*)d_out);
}

// Round 6
// 286.133 us; speedup vs baseline: 2.3757x; 2.3757x over previous
//
#include <hip/hip_runtime.h>
#include <math.h>

// FineGrainLoss: B=96, n1=196 (image tokens), n2=77 (text tokens), d=512.
#define BB 96
#define N1 196
#define N2 77
#define DD 512

#define IMGN (BB * N1 * DD)
#define TXTN (BB * N2 * DD)

// R15 TILED-H16: sim kernel is byte-for-byte R1 (the proven 233-µs
// structure: 512 thr / 8 waves 4x2, BK=32, 3 buffers, prefetch dist 2,
// counted vmcnt, 2 barriers/step) — but h16 is PRE-TILED by the convert
// pass: each 1-KB MFMA tile (16 rows x 32 k, cell = lq*16+lm) contiguous,
// layout [bi][13 strips][16 kc] then [bt][5 cts][16 kc].
// WHY: R1/R3/R4 all pinned at 233 µs with all pipes <=30%. Shared
// invariant = staging access pattern: each wave-load fetched 16 scattered
// 64-B segments (rows 1 KB apart) -> read path measured 11.9 B/cyc/CU.
// m97's contiguous staging through the same gload_lds engine: 21.8 B/cyc.
// Pre-tiling makes every staging instr read a contiguous 1 KB (full
// 128-B lines), targeting ~2x staging throughput.
// LESSONS CARRIED: (R11) never force occupancy via launch_bounds — acc
// spills, WRITE_SIZE balloons. (R14) no reg-staging — +36 regs spills acc.
#define ATILES 13
#define NTILES 24              // 23 real + 1 dummy (3 stage-loads per wave)
#define BUFH (NTILES * 512)    // _Float16 per buffer (24,576 B)

#define TA_TILES (BB * 13 * 16)            // 19,968 A tiles
#define TB_TILES (BB * 5 * 16)             //  7,680 B tiles
#define NT_TILES (TA_TILES + TB_TILES)     // 27,648 tiles (28.3 MB)

typedef _Float16 f16x8 __attribute__((ext_vector_type(8)));  // 8 f16 (4 VGPR)
typedef float f4v __attribute__((ext_vector_type(4)));       // MFMA C/D

typedef unsigned int __attribute__((address_space(1))) as1_uint;
typedef unsigned int __attribute__((address_space(3))) as3_uint;

__device__ __forceinline__ void gload_lds16(const void* g, void* l) {
    __builtin_amdgcn_global_load_lds((const as1_uint*)g, (as3_uint*)l, 16, 0, 0);
}

// fp32 -> f16 convert + TILE pass. One thread per 16-B cell.
// Thread -> (tile t, c' = row16*4 + k8): 4 consecutive threads read 128 B
// contiguous of one source row (coalesced); write lands at cell
// c = k8*16 + row16 of the 1-KB tile (scattered 16-B, write-combined).
// Tile content: cell c holds row (base+ (c&15)), k = kc*32 + (c>>4)*8 —
// exactly the LDS cell layout compute_sub consumes (lane = lq*16+lm).
__global__ void convert_tiled_kernel(const float* __restrict__ img,
                                     const float* __restrict__ txt,
                                     _Float16* __restrict__ dst) {
    const int tid = blockIdx.x * blockDim.x + threadIdx.x;
    if (tid >= NT_TILES * 64) return;
    const int t     = tid >> 6;
    const int cp    = tid & 63;
    const int row16 = cp >> 2;
    const int k8    = cp & 3;
    const float* src;
    if (t < TA_TILES) {
        const int kc = t & 15;
        const int s  = (t >> 4) % 13;
        const int bi = t / (13 * 16);
        int q = s * 16 + row16; q = q > (N1 - 1) ? (N1 - 1) : q;
        src = img + (size_t)(bi * N1 + q) * DD + kc * 32 + k8 * 8;
    } else {
        const int tt = t - TA_TILES;
        const int kc = tt & 15;
        const int ct = (tt >> 4) % 5;
        const int bt = tt / (5 * 16);
        int r = ct * 16 + row16; r = r > (N2 - 1) ? (N2 - 1) : r;
        src = txt + (size_t)(bt * N2 + r) * DD + kc * 32 + k8 * 8;
    }
    float4 v0 = *(const float4*)src;
    float4 v1 = *(const float4*)(src + 4);
    union { _Float16 h[8]; uint4 u; } o;
    o.h[0] = (_Float16)v0.x; o.h[1] = (_Float16)v0.y;
    o.h[2] = (_Float16)v0.z; o.h[3] = (_Float16)v0.w;
    o.h[4] = (_Float16)v1.x; o.h[5] = (_Float16)v1.y;
    o.h[6] = (_Float16)v1.z; o.h[7] = (_Float16)v1.w;
    const int c = k8 * 16 + row16;
    *(uint4*)(dst + (size_t)t * 512 + c * 8) = o.u;
}

// One K=32 sub-step: wave (g,h) computes strips [SG0, SG0+NS) x 5 cts of
// bt-half H. A strip s at tile s; B ct of half H at tile ATILES + H*5 + ct.
template <int SG0, int NS, int H>
__device__ __forceinline__ void compute_sub(const f16x8* __restrict__ fr,
                                            f4v* __restrict__ acc, int lane) {
    f16x8 b[5];
#pragma unroll
    for (int ct = 0; ct < 5; ++ct)
        b[ct] = fr[(ATILES + H * 5 + ct) * 64 + lane];
#pragma unroll
    for (int i = 0; i < NS; ++i) {
        f16x8 a = fr[(SG0 + i) * 64 + lane];
#pragma unroll
        for (int ct = 0; ct < 5; ++ct)
            acc[i * 5 + ct] = __builtin_amdgcn_mfma_f32_16x16x32_f16(
                a, b[ct], acc[i * 5 + ct], 0, 0, 0);
    }
}

// Reduction partials. C/D layout: col = lane&15, row = (lane>>4)*4 + reg.
// rp[H*208 + q]: per-bt-half rowmax (each (H, strip) owned by one wave).
// cp[g*160 + H*80 + col]: colmax partial per strip-group.
template <int SG0, int NS, int H>
__device__ __forceinline__ void reduce_phase1(const f4v* __restrict__ acc,
                                              int g, int lq, int lm,
                                              float* __restrict__ rp,
                                              float* __restrict__ cp) {
    float colm[5];
#pragma unroll
    for (int ct = 0; ct < 5; ++ct) colm[ct] = -INFINITY;
#pragma unroll
    for (int i = 0; i < NS; ++i) {
        const int s = SG0 + i;
        float rowm[4] = {-INFINITY, -INFINITY, -INFINITY, -INFINITY};
        bool rows_ok = (s != 12) || (lq == 0);   // rows >=196 are clamp-dups
#pragma unroll
        for (int ct = 0; ct < 5; ++ct) {
            f4v a = acc[i * 5 + ct];
            bool col_ok = (ct != 4) || (lm < N2 - 64);   // cols >=77 dups
            float cm = fmaxf(fmaxf(a[0], a[1]), fmaxf(a[2], a[3]));
            colm[ct] = fmaxf(colm[ct], rows_ok ? cm : -INFINITY);
#pragma unroll
            for (int r = 0; r < 4; ++r)
                rowm[r] = fmaxf(rowm[r], col_ok ? a[r] : -INFINITY);
        }
#pragma unroll
        for (int r = 0; r < 4; ++r) {
            float m = rowm[r];
            m = fmaxf(m, __shfl_xor(m, 1));
            m = fmaxf(m, __shfl_xor(m, 2));
            m = fmaxf(m, __shfl_xor(m, 4));
            m = fmaxf(m, __shfl_xor(m, 8));
            if (lm == 0) rp[H * 208 + s * 16 + lq * 4 + r] = m;
        }
    }
#pragma unroll
    for (int ct = 0; ct < 5; ++ct) {
        float m = colm[ct];
        m = fmaxf(m, __shfl_xor(m, 16));
        m = fmaxf(m, __shfl_xor(m, 32));
        if (lq == 0) cp[g * 160 + H * 80 + ct * 16 + lm] = m;
    }
}

// One block per (bi, btPair): S[208x160] = img[bi].(txt[bt0]|txt[bt1])^T.
// 512 threads = 8 waves in a 4x2 grid: strip-groups {4,3,3,3} x bt-half.
// __launch_bounds__(512,4): total-reg cap 128/wave -> no spill (acc[20]
// = 80 f32 in AGPRs + ~45 VGPRs). Do NOT raise the min-waves arg.
template <bool PRE>
__global__ __launch_bounds__(512, 4) void sim_mfma_kernel(
    const float* __restrict__ imgF, const float* __restrict__ txtF,
    const _Float16* __restrict__ h16,   // TILED (see convert_tiled_kernel)
    float* __restrict__ i2t, float* __restrict__ t2i)
{
    // ---- XCD-locality swizzle (4608 blocks = 8 xcd x 12 bi x 48 btPairs) ----
    const int id  = blockIdx.x;
    const int xcd = id & 7;
    const int lid = id >> 3;           // 0..575
    const int w   = lid % 48;
    const int btq = lid / 48;          // 0..11
    const int btp = btq * 4 + (w & 3); // 0..47
    const int bi  = xcd * 12 + (w >> 2);
    const int bt0 = btp * 2;

    const int tid = threadIdx.x;
    const int wave = tid >> 6, lane = tid & 63;
    const int lm = lane & 15;
    const int lq = lane >> 4;
    const int g = wave >> 1;           // strip-group 0..3
    // const int h = wave & 1;         // bt-half (baked into templates)

    __shared__ __align__(16) _Float16 lds[3 * BUFH];   // 73,728 B
    // epilogue scratch aliases buffer 0: last compute (kc=15) reads buffer
    // 15%3=0, but its end-of-step barrier B separates all readers from the
    // reduction writes below.
    float* rp   = (float*)lds;           // 416: [half][208] rowmax
    float* cp   = (float*)lds + 416;     // 640: [g][160] colmax partials
    float* sws  = (float*)lds + 1056;    // 8
    float* scol = (float*)lds + 1064;    // 160

    // ---- staging descriptors ----
    // Thread stages cell `lane` of tile T = 8j + wave, j=0..2 (24 tiles,
    // exactly 3 per wave). PRE path: h16 is tiled — off = tileBase*512 +
    // lane*8; stage adds kc*512 (consecutive kc tiles are adjacent 1-KB
    // blocks -> each gload_lds reads a CONTIGUOUS 1 KB).
    int off[3];
    const float* fsrc[3];
#pragma unroll
    for (int j = 0; j < 3; ++j) {
        const int T = 8 * j + wave;
        if constexpr (PRE) {
            int t;
            if (T < ATILES) {
                t = (bi * 13 + T) * 16;
            } else if (T < 23) {
                const int ct = T - ATILES;      // 0..9
                const int bt = bt0 + (ct >= 5);
                t = TA_TILES + (bt * 5 + (ct % 5)) * 16;
            } else {
                t = 0;   // dummy tile: re-reads A tile 0, content never used
            }
            off[j] = t * 512 + lane * 8;
        } else {
            int o;
            bool isA = true;
            if (T < ATILES) {
                int q = T * 16 + lm; q = q > (N1 - 1) ? (N1 - 1) : q;
                o = (bi * N1 + q) * DD + lq * 8;
            } else if (T < 23) {
                isA = false;
                int ct = T - ATILES;
                int bt = bt0 + (ct >= 5);
                int r = (ct % 5) * 16 + lm; r = r > (N2 - 1) ? (N2 - 1) : r;
                o = (bt * N2 + r) * DD + lq * 8;
            } else {
                o = lq * 8;
            }
            off[j] = o;
            fsrc[j] = isA ? imgF : txtF;
        }
    }

    // async staging of K32 chunk kc into buffer b (3 gload_lds per wave,
    // each a contiguous 1-KB tile read)
    auto stage = [&](int kc, int b) {
        const int k0 = kc * 512;
#pragma unroll
        for (int j = 0; j < 3; ++j)
            gload_lds16(h16 + off[j] + k0,
                        lds + (b * NTILES + 8 * j + wave) * 512);
    };

    f4v acc[20];   // waves 0,1 (4-strip group): 20; others: 15 (tail dead)
#pragma unroll
    for (int i = 0; i < 20; ++i) acc[i] = (f4v){0.f, 0.f, 0.f, 0.f};

    auto do_compute = [&](const f16x8* fr) {
        if (wave == 0)      compute_sub<0, 4, 0>(fr, acc, lane);
        else if (wave == 1) compute_sub<0, 4, 1>(fr, acc, lane);
        else if (wave == 2) compute_sub<4, 3, 0>(fr, acc, lane);
        else if (wave == 3) compute_sub<4, 3, 1>(fr, acc, lane);
        else if (wave == 4) compute_sub<7, 3, 0>(fr, acc, lane);
        else if (wave == 5) compute_sub<7, 3, 1>(fr, acc, lane);
        else if (wave == 6) compute_sub<10, 3, 0>(fr, acc, lane);
        else                compute_sub<10, 3, 1>(fr, acc, lane);
    };

    if constexpr (PRE) {
        // ---- K loop: 16 steps of BK=32, 3 buffers, prefetch distance 2.
        // Counted vmcnt: each wave holds 3 loads/step, <=9 in flight;
        // vmcnt(6) waits only for the step about to be computed, so the
        // two younger steps' DMA stays in flight across both barriers.
        // Barrier A: all waves' loads for buf kc landed.
        // Barrier B: all waves done reading buf kc%3 before the DMA issued
        // next iteration (stage kc+3) overwrites it.
        stage(0, 0);
        stage(1, 1);
#pragma unroll 1
        for (int kc = 0; kc < 16; ++kc) {
            if (kc < 14) {
                stage(kc + 2, (kc + 2) % 3);
                asm volatile("s_waitcnt vmcnt(6)" ::: "memory");
            } else if (kc == 14) {
                asm volatile("s_waitcnt vmcnt(3)" ::: "memory");
            } else {
                asm volatile("s_waitcnt vmcnt(0)" ::: "memory");
            }
            __builtin_amdgcn_s_barrier();          // A
            asm volatile("" ::: "memory");
            do_compute((const f16x8*)(lds + (kc % 3) * BUFH));
            asm volatile("" ::: "memory");
            __builtin_amdgcn_s_barrier();          // B
        }
    } else {
        // correctness fallback (workspace too small): sync single-buffer
#pragma unroll 1
        for (int kc = 0; kc < 16; ++kc) {
            __syncthreads();
            const int k0 = kc * 32;
#pragma unroll
            for (int j = 0; j < 3; ++j) {
                const int T = 8 * j + wave;
                if (T < 23) {
                    float4 v0 = *(const float4*)(fsrc[j] + off[j] + k0);
                    float4 v1 = *(const float4*)(fsrc[j] + off[j] + k0 + 4);
                    union { f16x8 f; uint4 u; } o;
                    o.f[0] = (_Float16)v0.x; o.f[1] = (_Float16)v0.y;
                    o.f[2] = (_Float16)v0.z; o.f[3] = (_Float16)v0.w;
                    o.f[4] = (_Float16)v1.x; o.f[5] = (_Float16)v1.y;
                    o.f[6] = (_Float16)v1.z; o.f[7] = (_Float16)v1.w;
                    ((uint4*)lds)[T * 64 + lane] = o.u;
                }
            }
            __syncthreads();
            do_compute((const f16x8*)lds);
        }
        __syncthreads();
    }

    // ---- fused reductions (LDS buffer re-used as scratch) ----
    if (wave == 0)      reduce_phase1<0, 4, 0>(acc, g, lq, lm, rp, cp);
    else if (wave == 1) reduce_phase1<0, 4, 1>(acc, g, lq, lm, rp, cp);
    else if (wave == 2) reduce_phase1<4, 3, 0>(acc, g, lq, lm, rp, cp);
    else if (wave == 3) reduce_phase1<4, 3, 1>(acc, g, lq, lm, rp, cp);
    else if (wave == 4) reduce_phase1<7, 3, 0>(acc, g, lq, lm, rp, cp);
    else if (wave == 5) reduce_phase1<7, 3, 1>(acc, g, lq, lm, rp, cp);
    else if (wave == 6) reduce_phase1<10, 3, 0>(acc, g, lq, lm, rp, cp);
    else                reduce_phase1<10, 3, 1>(acc, g, lq, lm, rp, cp);
    __syncthreads();

    // i2t: mean over q<196 of rowmax, per bt-half.
    // Waves 0-3 (tid 0-255) cover half 0; waves 4-7 cover half 1.
    {
        const int half = tid >> 8;
        const int t = tid & 255;
        float v = (t < N1) ? rp[half * 208 + t] : 0.f;
        v += __shfl_xor(v, 1);  v += __shfl_xor(v, 2);  v += __shfl_xor(v, 4);
        v += __shfl_xor(v, 8);  v += __shfl_xor(v, 16); v += __shfl_xor(v, 32);
        if (lane == 0) sws[wave] = v;
    }
    // colmax merge across strip-groups
    if (tid < 160) {
        float m = fmaxf(fmaxf(cp[tid], cp[160 + tid]),
                        fmaxf(cp[320 + tid], cp[480 + tid]));
        scol[tid] = m;
    }
    __syncthreads();
    if (tid == 0)
        i2t[bi * BB + bt0] =
            (sws[0] + sws[1] + sws[2] + sws[3]) * (1.f / (float)N1);
    if (tid == 1)
        i2t[bi * BB + bt0 + 1] =
            (sws[4] + sws[5] + sws[6] + sws[7]) * (1.f / (float)N1);
    // t2i: mean over r<77 of colmax; wave0 -> bt0 (cols 0-79), wave1 -> bt1.
    if (wave < 2) {
        const float* c = scol + wave * 80;
        float cv = c[lane] + ((lane < N2 - 64) ? c[64 + lane] : 0.f);
        cv += __shfl_xor(cv, 1);  cv += __shfl_xor(cv, 2);  cv += __shfl_xor(cv, 4);
        cv += __shfl_xor(cv, 8);  cv += __shfl_xor(cv, 16); cv += __shfl_xor(cv, 32);
        if (lane == 0)
            t2i[(bt0 + wave) * BB + bi] = cv * (1.f / (float)N2);
    }
}

// CE with arange labels over both [B,B] logit matrices.
__global__ __launch_bounds__(256) void ce_kernel(
    const float* __restrict__ i2t, const float* __restrict__ t2i,
    float* __restrict__ out)
{
    const int tid = threadIdx.x;
    const int wid = tid >> 6;
    const int lane = tid & 63;

    float contrib = 0.f;
    if (tid < 2 * BB) {
        const float* M = (tid < BB) ? i2t : t2i;
        const int b = (tid < BB) ? tid : tid - BB;
        const float* row = M + b * BB;
        float mx = row[0];
#pragma unroll 1
        for (int c = 1; c < BB; ++c) mx = fmaxf(mx, row[c]);
        float s = 0.f;
#pragma unroll 1
        for (int c = 0; c < BB; ++c) s += expf(row[c] - mx);
        float lse = mx + logf(s);
        contrib = row[b] - lse;
    }
    contrib += __shfl_xor(contrib, 1);
    contrib += __shfl_xor(contrib, 2);
    contrib += __shfl_xor(contrib, 4);
    contrib += __shfl_xor(contrib, 8);
    contrib += __shfl_xor(contrib, 16);
    contrib += __shfl_xor(contrib, 32);

    __shared__ float s_part[4];
    if (lane == 0) s_part[wid] = contrib;
    __syncthreads();
    if (tid == 0) {
        float total = s_part[0] + s_part[1] + s_part[2] + s_part[3];
        out[0] = -total * (1.f / (float)(2 * BB));
    }
}

extern "C" void kernel_launch(void* const* d_in, const int* in_sizes, int n_in,
                              void* d_out, int out_size, void* d_ws, size_t ws_size,
                              hipStream_t stream) {
    const float* img = (const float*)d_in[0];   // [96,196,512] fp32
    const float* txt = (const float*)d_in[1];   // [96,77,512] fp32
    float* i2t = (float*)d_ws;                  // [96,96]
    float* t2i = i2t + BB * BB;                 // [96,96]

    const size_t conv_off = 2 * BB * BB * sizeof(float);   // 16B-aligned
    const size_t need = conv_off + (size_t)NT_TILES * 512 * sizeof(_Float16);

    const int nblocks = BB * (BB / 2);   // 4608 = (bi, btPair)
    if (ws_size >= need) {
        _Float16* h16 = (_Float16*)((char*)d_ws + conv_off);
        const int nthr = NT_TILES * 64;
        convert_tiled_kernel<<<(nthr + 255) / 256, 256, 0, stream>>>(img, txt, h16);
        sim_mfma_kernel<true><<<nblocks, 512, 0, stream>>>(img, txt, h16, i2t, t2i);
    } else {
        sim_mfma_kernel<false><<<nblocks, 512, 0, stream>>>(img, txt, nullptr, i2t, t2i);
    }
    ce_kernel<<<1, 256, 0, stream>>>(i2t, t2i, (float*)d_out);
}